// Round 1
// baseline (196.335 us; speedup 1.0000x reference)
//
#include <hip/hip_runtime.h>

#define N_NODES 4096
#define C_CH    128
#define E_ELEM  10

// ws layout (bytes):
//   [0,40)      hist   (10 int)
//   [64,108)    starts (11 int)
//   [128,168)   cursor (10 int)
//   [256,+16KB) elem   (4096 int)
//   [16640,+16KB) jlist (4096 int)
//   [40960,+8.39MB) bout (float) [c][slot(4)][N]   slot0 = L0; slot1..3 = L1 m=0..2

__global__ void k_elem_hist(const float* __restrict__ attrs, int* __restrict__ elem,
                            int* __restrict__ hist) {
    int n = blockIdx.x * blockDim.x + threadIdx.x;
    if (n >= N_NODES) return;
    const float* a = attrs + n * E_ELEM;
    float best = a[0];
    int e = 0;
#pragma unroll
    for (int k = 1; k < E_ELEM; ++k) {
        float v = a[k];
        if (v > best) { best = v; e = k; }
    }
    elem[n] = e;
    atomicAdd(&hist[e], 1);
}

__global__ void k_prefix(const int* __restrict__ hist, int* __restrict__ starts,
                         int* __restrict__ cursor) {
    if (threadIdx.x == 0) {
        int s = 0;
        for (int e = 0; e < E_ELEM; ++e) {
            starts[e] = s;
            cursor[e] = s;
            s += hist[e];
        }
        starts[E_ELEM] = s;
    }
}

__global__ void k_scatter(const int* __restrict__ elem, int* __restrict__ cursor,
                          int* __restrict__ jlist) {
    int n = blockIdx.x * blockDim.x + threadIdx.x;
    if (n >= N_NODES) return;
    int e = elem[n];
    int pos = atomicAdd(&cursor[e], 1);
    jlist[pos] = n;
}

// contract one m-block for two nodes sharing the broadcast V reads.
// V3 layout: [(a*9+b)*12 + i], i=0..8 cubic coeffs, slot 9 = V2[a,b]. V1: [a].
__device__ __forceinline__ float2 contract2(const float* __restrict__ V3,
                                            const float* __restrict__ V1,
                                            const float (&xA)[9], const float (&xB)[9]) {
    float rA = 0.f, rB = 0.f;
#pragma unroll 3
    for (int a = 0; a < 9; ++a) {
        float v1a = V1[a];
        float aA = v1a, aB = v1a;
#pragma unroll
        for (int b = 0; b < 9; ++b) {
            const float* v = V3 + (a * 9 + b) * 12;
            float4 v0 = *reinterpret_cast<const float4*>(v);
            float4 v4 = *reinterpret_cast<const float4*>(v + 4);
            float2 v8 = *reinterpret_cast<const float2*>(v + 8);  // v8.x = V3 i=8, v8.y = V2
            // node A: 3 parallel chains
            float pA0 = fmaf(v0.w, xA[3], fmaf(v0.x, xA[0], v8.y));
            pA0 = fmaf(v4.z, xA[6], pA0);
            float pA1 = fmaf(v4.x, xA[4], v0.y * xA[1]);
            pA1 = fmaf(v4.w, xA[7], pA1);
            float pA2 = fmaf(v4.y, xA[5], v0.z * xA[2]);
            pA2 = fmaf(v8.x, xA[8], pA2);
            float tA = (pA0 + pA1) + pA2;
            aA = fmaf(tA, xA[b], aA);
            // node B
            float pB0 = fmaf(v0.w, xB[3], fmaf(v0.x, xB[0], v8.y));
            pB0 = fmaf(v4.z, xB[6], pB0);
            float pB1 = fmaf(v4.x, xB[4], v0.y * xB[1]);
            pB1 = fmaf(v4.w, xB[7], pB1);
            float pB2 = fmaf(v4.y, xB[5], v0.z * xB[2]);
            pB2 = fmaf(v8.x, xB[8], pB2);
            float tB = (pB0 + pB1) + pB2;
            aB = fmaf(tB, xB[b], aB);
        }
        rA = fmaf(aA, xA[a], rA);
        rB = fmaf(aB, xB[a], rB);
    }
    return make_float2(rA, rB);
}

__global__ __launch_bounds__(128) void k_contract(
    const float* __restrict__ x, const int* __restrict__ jlist,
    const int* __restrict__ starts,
    const float* __restrict__ U3_0, const float* __restrict__ U2_0,
    const float* __restrict__ U1_0, const float* __restrict__ W3_0,
    const float* __restrict__ W2_0, const float* __restrict__ W1_0,
    const float* __restrict__ U3_1, const float* __restrict__ U2_1,
    const float* __restrict__ U1_1, const float* __restrict__ W3_1,
    const float* __restrict__ W2_1, const float* __restrict__ W1_1,
    float* __restrict__ bout) {
    // V3 arrays padded to stride 12 (i slot 9 holds V2; 10,11 unused)
    __shared__ __align__(16) float sV3_1[3 * 81 * 12];  // L=1, m-major
    __shared__ __align__(16) float sV3_0[81 * 12];      // L=0
    __shared__ float sV1_1[27];
    __shared__ float sV1_0[9];

    const int c = blockIdx.x & 127;
    const int e = blockIdx.x >> 7;
    const int tid = threadIdx.x;

    // ---- fold W into U for this (e,c): fill LDS ----
    for (int t = tid; t < 3276; t += 128) {
        if (t < 2187) {                       // V3_1: t = ((m*9+a)*9+b)*9 + i
            float s = 0.f;
#pragma unroll
            for (int p = 0; p < 7; ++p)
                s = fmaf(U3_1[t * 7 + p], W3_1[(e * 7 + p) * C_CH + c], s);
            sV3_1[(t / 9) * 12 + (t % 9)] = s;
        } else if (t < 2916) {                // V3_0
            int tt = t - 2187;
            float s = 0.f;
#pragma unroll
            for (int p = 0; p < 5; ++p)
                s = fmaf(U3_0[tt * 5 + p], W3_0[(e * 5 + p) * C_CH + c], s);
            sV3_0[(tt / 9) * 12 + (tt % 9)] = s;
        } else if (t < 3159) {                // V2_1 -> pad slot 9
            int tt = t - 2916;
            float s = 0.f;
#pragma unroll
            for (int p = 0; p < 3; ++p)
                s = fmaf(U2_1[tt * 3 + p], W2_1[(e * 3 + p) * C_CH + c], s);
            sV3_1[tt * 12 + 9] = s;
        } else if (t < 3240) {                // V2_0 -> pad slot 9
            int tt = t - 3159;
            float s = fmaf(U2_0[tt * 2 + 0], W2_0[(e * 2 + 0) * C_CH + c],
                           U2_0[tt * 2 + 1] * W2_0[(e * 2 + 1) * C_CH + c]);
            sV3_0[tt * 12 + 9] = s;
        } else if (t < 3267) {                // V1_1
            int tt = t - 3240;
            sV1_1[tt] = U1_1[tt] * W1_1[e * C_CH + c];
        } else {                              // V1_0
            int tt = t - 3267;
            sV1_0[tt] = U1_0[tt] * W1_0[e * C_CH + c];
        }
    }
    __syncthreads();

    const int s0 = starts[e];
    const int s1 = starts[e + 1];
    const int cnt = s1 - s0;
    const int half = (cnt + 1) >> 1;

    for (int idx = tid; idx < half; idx += 128) {
        const int jA = s0 + idx;
        const int jB = jA + half;
        const bool hasB = (jB < s1);
        const int nA = jlist[jA];
        const int nB = hasB ? jlist[jB] : nA;
        const float* pA = x + (nA * C_CH + c) * 9;
        const float* pB = x + (nB * C_CH + c) * 9;
        float xA[9], xB[9];
#pragma unroll
        for (int i = 0; i < 9; ++i) { xA[i] = pA[i]; xB[i] = pB[i]; }

        // L = 0 (slot 0)
        {
            float2 r = contract2(sV3_0, sV1_0, xA, xB);
            bout[(c * 4 + 0) * N_NODES + jA] = r.x;
            if (hasB) bout[(c * 4 + 0) * N_NODES + jB] = r.y;
        }
        // L = 1, m = 0..2 (slots 1..3)
        for (int mm = 0; mm < 3; ++mm) {
            float2 r = contract2(sV3_1 + mm * 81 * 12, sV1_1 + mm * 9, xA, xB);
            bout[(c * 4 + 1 + mm) * N_NODES + jA] = r.x;
            if (hasB) bout[(c * 4 + 1 + mm) * N_NODES + jB] = r.y;
        }
    }
}

__global__ __launch_bounds__(512) void k_linear(
    const float* __restrict__ bout, const int* __restrict__ jlist,
    const float* __restrict__ Wl0, const float* __restrict__ Wl1,
    const float* __restrict__ sc, float* __restrict__ out) {
    const int col = threadIdx.x;         // 0..511 output column
    const int jbase = blockIdx.x * 16;   // 16 j's per block
    int d, slot;
    const float* Wl;
    if (col < 128) { d = col; slot = 0; Wl = Wl0; }
    else {
        int q = col - 128;
        d = q / 3;
        slot = 1 + q % 3;
        Wl = Wl1;
    }
    float acc[16];
#pragma unroll
    for (int q = 0; q < 16; ++q) acc[q] = 0.f;

    for (int cc = 0; cc < C_CH; ++cc) {
        float w = Wl[cc * C_CH + d];
        const float4* bp =
            reinterpret_cast<const float4*>(bout + (cc * 4 + slot) * N_NODES + jbase);
#pragma unroll
        for (int q = 0; q < 4; ++q) {
            float4 v = bp[q];
            acc[q * 4 + 0] = fmaf(w, v.x, acc[q * 4 + 0]);
            acc[q * 4 + 1] = fmaf(w, v.y, acc[q * 4 + 1]);
            acc[q * 4 + 2] = fmaf(w, v.z, acc[q * 4 + 2]);
            acc[q * 4 + 3] = fmaf(w, v.w, acc[q * 4 + 3]);
        }
    }

    const float inv = 0.08838834764831845f;  // 1/sqrt(128)
#pragma unroll
    for (int jj = 0; jj < 16; ++jj) {
        int n = jlist[jbase + jj];
        out[n * 512 + col] = fmaf(acc[jj], inv, sc[n * 512 + col]);
    }
}

extern "C" void kernel_launch(void* const* d_in, const int* in_sizes, int n_in,
                              void* d_out, int out_size, void* d_ws, size_t ws_size,
                              hipStream_t stream) {
    const float* x     = (const float*)d_in[0];
    const float* sc    = (const float*)d_in[1];
    const float* attrs = (const float*)d_in[2];
    const float* U3_0 = (const float*)d_in[3];
    const float* U2_0 = (const float*)d_in[4];
    const float* U1_0 = (const float*)d_in[5];
    const float* W3_0 = (const float*)d_in[6];
    const float* W2_0 = (const float*)d_in[7];
    const float* W1_0 = (const float*)d_in[8];
    const float* Wl0  = (const float*)d_in[9];
    const float* U3_1 = (const float*)d_in[10];
    const float* U2_1 = (const float*)d_in[11];
    const float* U1_1 = (const float*)d_in[12];
    const float* W3_1 = (const float*)d_in[13];
    const float* W2_1 = (const float*)d_in[14];
    const float* W1_1 = (const float*)d_in[15];
    const float* Wl1  = (const float*)d_in[16];

    char* ws = (char*)d_ws;
    int* hist   = (int*)(ws + 0);
    int* starts = (int*)(ws + 64);
    int* cursor = (int*)(ws + 128);
    int* elem   = (int*)(ws + 256);
    int* jlist  = (int*)(ws + 256 + 16384);
    float* bout = (float*)(ws + 40960);

    hipMemsetAsync(hist, 0, E_ELEM * sizeof(int), stream);
    k_elem_hist<<<16, 256, 0, stream>>>(attrs, elem, hist);
    k_prefix<<<1, 64, 0, stream>>>(hist, starts, cursor);
    k_scatter<<<16, 256, 0, stream>>>(elem, cursor, jlist);
    k_contract<<<1280, 128, 0, stream>>>(x, jlist, starts,
                                         U3_0, U2_0, U1_0, W3_0, W2_0, W1_0,
                                         U3_1, U2_1, U1_1, W3_1, W2_1, W1_1,
                                         bout);
    k_linear<<<256, 512, 0, stream>>>(bout, jlist, Wl0, Wl1, sc, (float*)d_out);
}